// Round 1
// baseline (15037.262 us; speedup 1.0000x reference)
//
#include <hip/hip_runtime.h>
#include <hip/hip_bf16.h>

#define SEQ 256
#define NB 16
#define HID 512
#define VOC 32000

typedef short bf16x8 __attribute__((ext_vector_type(8)));
typedef float f32x4 __attribute__((ext_vector_type(4)));

__device__ __forceinline__ void ld_lds16(const void* g, void* l) {
  __builtin_amdgcn_global_load_lds((const __attribute__((address_space(1))) void*)g,
                                   (__attribute__((address_space(3))) void*)l, 16, 0, 0);
}

__device__ __forceinline__ float sigf(float x) { return 1.0f / (1.0f + expf(-x)); }

// ---------------- embedding gather: xe[s][b][:] = emb[x[b][s]][:] ----------------
__global__ void embed_k(const int* __restrict__ x, const float* __restrict__ emb,
                        float* __restrict__ xe) {
  int bid = blockIdx.x;  // = s*16 + b
  int s = bid >> 4, b = bid & 15;
  int tok = x[b * SEQ + s];
  const float4* src = (const float4*)(emb + (size_t)tok * HID);
  float4* dst = (float4*)(xe + ((size_t)s * NB + b) * HID);
  dst[threadIdx.x] = src[threadIdx.x];
}

// ---------------- f32 -> bf16 (RNE) pack, 8 elements/thread ----------------
__device__ __forceinline__ unsigned pk2(float a, float b) {
  __hip_bfloat16 ha = __float2bfloat16(a), hb = __float2bfloat16(b);
  unsigned short ua = *(unsigned short*)&ha, ub = *(unsigned short*)&hb;
  return (unsigned)ua | ((unsigned)ub << 16);
}

__global__ void cvt_k(const float* __restrict__ in, uint4* __restrict__ out) {
  size_t i = (size_t)blockIdx.x * blockDim.x + threadIdx.x;
  const float4* in4 = (const float4*)in;
  float4 a = in4[i * 2], b = in4[i * 2 + 1];
  uint4 o;
  o.x = pk2(a.x, a.y);
  o.y = pk2(a.z, a.w);
  o.z = pk2(b.x, b.y);
  o.w = pk2(b.z, b.w);
  out[i] = o;
}

// ---------------- device-scope grid barrier (sense via generation counter) ----------------
__device__ __forceinline__ void gbar(unsigned* cnt, unsigned* gen, unsigned nb) {
  __syncthreads();
  if (threadIdx.x == 0) {
    unsigned g = __hip_atomic_load(gen, __ATOMIC_ACQUIRE, __HIP_MEMORY_SCOPE_AGENT);
    __threadfence();  // release: publish this block's global writes
    unsigned a = __hip_atomic_fetch_add(cnt, 1u, __ATOMIC_ACQ_REL, __HIP_MEMORY_SCOPE_AGENT);
    if (a == nb - 1u) {
      __hip_atomic_store(cnt, 0u, __ATOMIC_RELAXED, __HIP_MEMORY_SCOPE_AGENT);
      __hip_atomic_fetch_add(gen, 1u, __ATOMIC_RELEASE, __HIP_MEMORY_SCOPE_AGENT);
    } else {
      while (__hip_atomic_load(gen, __ATOMIC_RELAXED, __HIP_MEMORY_SCOPE_AGENT) == g)
        __builtin_amdgcn_s_sleep(2);
    }
    __threadfence();  // acquire: invalidate stale cached lines before next phase reads
  }
  __syncthreads();
}

// ---------------- persistent LSTM: 256 blocks, layer-pipelined wavefront ----------------
// blocks 0..127: layer 0 (h-cols slice*4..+4), blocks 128..255: layer 1.
// phase p: layer0 computes t=p, layer1 computes t=p-1.  257 grid barriers.
__global__ __launch_bounds__(256) void lstm_k(
    const float* __restrict__ Wih, const float* __restrict__ Whh,
    const float* __restrict__ bias, const float* __restrict__ xe,
    float* __restrict__ h1, float* __restrict__ h2,
    __hip_bfloat16* __restrict__ outs, unsigned* bar) {
  __shared__ float gbuf[16][17];
  __shared__ float c_lds[4][16];
  const int tid = threadIdx.x, bid = blockIdx.x;
  const int l = bid >> 7, slice = bid & 127;
  const int gl = tid >> 4, b = tid & 15;   // gate-row-local, batch
  const int q = gl >> 2, hl = gl & 3;      // gate type (i,f,g,o), local h col
  const int hc = slice * 4 + hl;
  const int j = q * HID + hc;              // gate row in [0,2048)
  const float4* w1 = (const float4*)(Wih + ((size_t)l * 2048 + j) * HID);
  const float4* w2 = (const float4*)(Whh + ((size_t)l * 2048 + j) * HID);
  const float bj = bias[l * 2048 + j];
  if (tid < 64) c_lds[tid >> 4][tid & 15] = 0.f;
  __syncthreads();
  for (int p = 0; p < SEQ + 1; ++p) {
    const int t = (l == 0) ? p : p - 1;
    const bool active = (l == 0) ? (p < SEQ) : (p >= 1);
    if (active) {
      const float* inp = (l == 0) ? (xe + (size_t)t * NB * HID)
                                  : (h1 + (size_t)(t & 1) * NB * HID);
      const float* hprev = ((l == 0) ? h1 : h2) + (size_t)((t + 1) & 1) * NB * HID;
      const float4* xv = (const float4*)(inp + b * HID);
      const float4* hv = (const float4*)(hprev + b * HID);
      float acc = bj;
#pragma unroll 4
      for (int k = 0; k < HID / 4; ++k) {
        float4 w = w1[k], v = xv[k];
        acc += w.x * v.x + w.y * v.y + w.z * v.z + w.w * v.w;
      }
#pragma unroll 4
      for (int k = 0; k < HID / 4; ++k) {
        float4 w = w2[k], v = hv[k];
        acc += w.x * v.x + w.y * v.y + w.z * v.z + w.w * v.w;
      }
      gbuf[gl][b] = acc;
    }
    __syncthreads();
    if (active && tid < 64) {
      const int b2 = tid & 15, h2l = tid >> 4;
      float iv = sigf(gbuf[h2l][b2]);
      float fv = sigf(gbuf[4 + h2l][b2]);
      float gv = tanhf(gbuf[8 + h2l][b2]);
      float ov = sigf(gbuf[12 + h2l][b2]);
      float cn = fv * c_lds[h2l][b2] + iv * gv;
      c_lds[h2l][b2] = cn;
      float hn = ov * tanhf(cn);
      float* hout = ((l == 0) ? h1 : h2) + (size_t)(t & 1) * NB * HID;
      hout[b2 * HID + slice * 4 + h2l] = hn;
      if (l == 1)
        outs[((size_t)b2 * SEQ + t) * HID + slice * 4 + h2l] = __float2bfloat16(hn);
    }
    gbar(bar, bar + 1, gridDim.x);
  }
}

// ---------------- FC GEMM: C[4096,32000] = A[4096,512](bf16) * B^T[32000,512](bf16) + bias ----------------
// m97-style: 128x128 tile, BK=32, global_load_lds width 16, 4 waves (2x2), 4x4 frags/wave.
__global__ __launch_bounds__(256) void fc_gemm(const __hip_bfloat16* __restrict__ A,
                                               const __hip_bfloat16* __restrict__ Bw,
                                               const float* __restrict__ bias,
                                               float* __restrict__ C) {
  __shared__ __align__(16) unsigned short lds_a[128 * 32];
  __shared__ __align__(16) unsigned short lds_b[128 * 32];
  const int tid = threadIdx.x;
  const int lane = tid & 63, wid = tid >> 6;
  const int m0 = blockIdx.y * 128, n0 = blockIdx.x * 128;
  const char* Ab = (const char*)A;   // row stride 1024 B (K=512 bf16)
  const char* Bb = (const char*)Bw;  // row stride 1024 B
  const int ra = tid >> 2;           // 0..63 rows per staging instr
  const int cb = (tid & 3) * 16;     // byte offset within 64B row-chunk
  f32x4 acc[4][4] = {};
  const int wm = (wid >> 1) * 64, wn = (wid & 1) * 64;
  const int fr = lane & 15, fk = (lane >> 4) * 8;
  for (int k0 = 0; k0 < HID; k0 += 32) {
    ld_lds16(Ab + (size_t)(m0 + ra) * 1024 + k0 * 2 + cb, (char*)lds_a + wid * 1024);
    ld_lds16(Ab + (size_t)(m0 + 64 + ra) * 1024 + k0 * 2 + cb,
             (char*)lds_a + 4096 + wid * 1024);
    ld_lds16(Bb + (size_t)(n0 + ra) * 1024 + k0 * 2 + cb, (char*)lds_b + wid * 1024);
    ld_lds16(Bb + (size_t)(n0 + 64 + ra) * 1024 + k0 * 2 + cb,
             (char*)lds_b + 4096 + wid * 1024);
    __syncthreads();
    bf16x8 af[4], bf[4];
#pragma unroll
    for (int i = 0; i < 4; ++i)
      af[i] = *(const bf16x8*)&lds_a[(wm + i * 16 + fr) * 32 + fk];
#pragma unroll
    for (int j = 0; j < 4; ++j)
      bf[j] = *(const bf16x8*)&lds_b[(wn + j * 16 + fr) * 32 + fk];
#pragma unroll
    for (int i = 0; i < 4; ++i)
#pragma unroll
      for (int j = 0; j < 4; ++j)
        acc[i][j] = __builtin_amdgcn_mfma_f32_16x16x32_bf16(af[i], bf[j], acc[i][j], 0, 0, 0);
    __syncthreads();
  }
  const int cr = (lane >> 4) * 4, cc = lane & 15;
  float bv[4];
#pragma unroll
  for (int jj = 0; jj < 4; ++jj) bv[jj] = bias[n0 + wn + jj * 16 + cc];
#pragma unroll
  for (int i = 0; i < 4; ++i) {
#pragma unroll
    for (int jj = 0; jj < 4; ++jj) {
      size_t base = (size_t)(m0 + wm + i * 16 + cr) * VOC + (size_t)(n0 + wn + jj * 16 + cc);
#pragma unroll
      for (int r = 0; r < 4; ++r) C[base + (size_t)r * VOC] = acc[i][jj][r] + bv[jj];
    }
  }
}

extern "C" void kernel_launch(void* const* d_in, const int* in_sizes, int n_in,
                              void* d_out, int out_size, void* d_ws, size_t ws_size,
                              hipStream_t stream) {
  const int* x = (const int*)d_in[0];
  const float* emb = (const float*)d_in[1];
  const float* Wih = (const float*)d_in[2];
  const float* Whh = (const float*)d_in[3];
  const float* bias = (const float*)d_in[4];
  const float* fcw = (const float*)d_in[5];
  const float* fcb = (const float*)d_in[6];
  float* out = (float*)d_out;
  char* ws = (char*)d_ws;
  float* wsf = (float*)ws;

  // ws layout (floats): [0:16) barrier | [16:16400) h1[2][16][512] | [16400:32784) h2
  //                     [32784:2129936) xe[256][16][512]
  // bytes: outs_bf16 @ 8519744 (4 MB), fcw_bf16 @ 12714048 (32.77 MB). total ~45.5 MB.
  unsigned* bar = (unsigned*)ws;
  float* h1 = wsf + 16;
  float* h2 = wsf + 16 + 16384;
  float* xe = wsf + 16 + 2 * 16384;
  __hip_bfloat16* outs_bf = (__hip_bfloat16*)(ws + 8519744);
  uint4* fcw_bf = (uint4*)(ws + 12714048);

  hipMemsetAsync(ws, 0, (16 + 2 * 16384) * 4, stream);  // barrier + h states = 0
  embed_k<<<SEQ * NB, 128, 0, stream>>>(x, emb, xe);
  cvt_k<<<8000, 256, 0, stream>>>(fcw, fcw_bf);  // 8000*256*8 = 16,384,000 elems
  lstm_k<<<256, 256, 0, stream>>>(Wih, Whh, bias, xe, h1, h2, outs_bf, bar);
  fc_gemm<<<dim3(250, 32), 256, 0, stream>>>(outs_bf, (const __hip_bfloat16*)fcw_bf, fcb, out);
}

// Round 2
// 13396.411 us; speedup vs baseline: 1.1225x; 1.1225x over previous
//
#include <hip/hip_runtime.h>
#include <hip/hip_bf16.h>

#define SEQ 256
#define NB 16
#define HID 512
#define VOC 32000

typedef short bf16x8 __attribute__((ext_vector_type(8)));
typedef float f32x4 __attribute__((ext_vector_type(4)));

__device__ __forceinline__ void ld_lds16(const void* g, void* l) {
  __builtin_amdgcn_global_load_lds((const __attribute__((address_space(1))) void*)g,
                                   (__attribute__((address_space(3))) void*)l, 16, 0, 0);
}

__device__ __forceinline__ float sigf(float x) { return 1.0f / (1.0f + expf(-x)); }

// ---------------- embedding gather: xe[s][b][:] = emb[x[b][s]][:] ----------------
__global__ void embed_k(const int* __restrict__ x, const float* __restrict__ emb,
                        float* __restrict__ xe) {
  int bid = blockIdx.x;  // = s*16 + b
  int s = bid >> 4, b = bid & 15;
  int tok = x[b * SEQ + s];
  const float4* src = (const float4*)(emb + (size_t)tok * HID);
  float4* dst = (float4*)(xe + ((size_t)s * NB + b) * HID);
  dst[threadIdx.x] = src[threadIdx.x];
}

// ---------------- f32 -> bf16 (RNE) pack, 8 elements/thread ----------------
__device__ __forceinline__ unsigned pk2(float a, float b) {
  __hip_bfloat16 ha = __float2bfloat16(a), hb = __float2bfloat16(b);
  unsigned short ua = *(unsigned short*)&ha, ub = *(unsigned short*)&hb;
  return (unsigned)ua | ((unsigned)ub << 16);
}

__global__ void cvt_k(const float* __restrict__ in, uint4* __restrict__ out) {
  size_t i = (size_t)blockIdx.x * blockDim.x + threadIdx.x;
  const float4* in4 = (const float4*)in;
  float4 a = in4[i * 2], b = in4[i * 2 + 1];
  uint4 o;
  o.x = pk2(a.x, a.y);
  o.y = pk2(a.z, a.w);
  o.z = pk2(b.x, b.y);
  o.w = pk2(b.z, b.w);
  out[i] = o;
}

// ---------------- two-level tree grid barrier ----------------
// bar word layout: root @ bar[0]; grp[g] @ bar[32+g*32]; gen-mirror[g] @ bar[544+g*32].
// 16 groups x 16 blocks. Each counter/mirror on its own 128B line:
//  - group adds contend 16-way on 16 independent lines (parallel),
//  - root adds contend 16-way on one line,
//  - each mirror line is polled by only 16 block-leaders.
__device__ __forceinline__ void gbar(unsigned* bar, int gid) {
  __syncthreads();
  if (threadIdx.x == 0) {
    unsigned* grp = bar + 32 + gid * 32;
    unsigned* mir = bar + 544 + gid * 32;
    unsigned g = __hip_atomic_load(mir, __ATOMIC_ACQUIRE, __HIP_MEMORY_SCOPE_AGENT);
    __threadfence();  // release this block's global writes
    bool bumped = false;
    unsigned a = __hip_atomic_fetch_add(grp, 1u, __ATOMIC_ACQ_REL, __HIP_MEMORY_SCOPE_AGENT);
    if (a == 15u) {
      __hip_atomic_store(grp, 0u, __ATOMIC_RELAXED, __HIP_MEMORY_SCOPE_AGENT);
      unsigned r = __hip_atomic_fetch_add(bar, 1u, __ATOMIC_ACQ_REL, __HIP_MEMORY_SCOPE_AGENT);
      if (r == 15u) {
        __hip_atomic_store(bar, 0u, __ATOMIC_RELAXED, __HIP_MEMORY_SCOPE_AGENT);
#pragma unroll
        for (int q = 0; q < 16; ++q)
          __hip_atomic_store(bar + 544 + q * 32, g + 1u, __ATOMIC_RELEASE,
                             __HIP_MEMORY_SCOPE_AGENT);
        bumped = true;
      }
    }
    if (!bumped)
      while (__hip_atomic_load(mir, __ATOMIC_RELAXED, __HIP_MEMORY_SCOPE_AGENT) == g)
        __builtin_amdgcn_s_sleep(4);
    __threadfence();  // acquire side
  }
  __syncthreads();
}

// ---------------- persistent LSTM: 256 blocks, layer-pipelined wavefront ----------------
// blocks 0..127: layer 0 (h-cols slice*4..+4), blocks 128..255: layer 1.
// phase p: layer0 computes t=p, layer1 computes t=p-1.  257 phases, tree barrier each.
__global__ __launch_bounds__(256) void lstm_k(
    const float* __restrict__ Wih, const float* __restrict__ Whh,
    const float* __restrict__ bias, const float* __restrict__ xe,
    float* __restrict__ h1, float* __restrict__ h2,
    __hip_bfloat16* __restrict__ outs, unsigned* bar) {
  __shared__ float gbuf[16][17];
  __shared__ float c_lds[4][16];
  const int tid = threadIdx.x, bid = blockIdx.x;
  const int l = bid >> 7, slice = bid & 127, gid = bid >> 4;
  const int gl = tid >> 4, b = tid & 15;   // gate-row-local, batch
  const int q = gl >> 2, hl = gl & 3;      // gate type (i,f,g,o), local h col
  const int hc = slice * 4 + hl;
  const int j = q * HID + hc;              // gate row in [0,2048)
  const float4* w1 = (const float4*)(Wih + ((size_t)l * 2048 + j) * HID);
  const float4* w2 = (const float4*)(Whh + ((size_t)l * 2048 + j) * HID);
  const float bj = bias[l * 2048 + j];
  if (tid < 64) c_lds[tid >> 4][tid & 15] = 0.f;
  __syncthreads();
  for (int p = 0; p < SEQ + 1; ++p) {
    const int t = (l == 0) ? p : p - 1;
    const bool active = (l == 0) ? (p < SEQ) : (p >= 1);
    if (active) {
      const float* inp = (l == 0) ? (xe + (size_t)t * NB * HID)
                                  : (h1 + (size_t)(t & 1) * NB * HID);
      const float* hprev = ((l == 0) ? h1 : h2) + (size_t)((t + 1) & 1) * NB * HID;
      const float4* xv = (const float4*)(inp + b * HID);
      const float4* hv = (const float4*)(hprev + b * HID);
      float ac0 = bj, ac1 = 0.f, ac2 = 0.f, ac3 = 0.f;
#pragma unroll 8
      for (int k = 0; k < HID / 4; k += 4) {
        float4 w, v;
        w = w1[k + 0]; v = xv[k + 0]; ac0 += w.x * v.x + w.y * v.y + w.z * v.z + w.w * v.w;
        w = w1[k + 1]; v = xv[k + 1]; ac1 += w.x * v.x + w.y * v.y + w.z * v.z + w.w * v.w;
        w = w1[k + 2]; v = xv[k + 2]; ac2 += w.x * v.x + w.y * v.y + w.z * v.z + w.w * v.w;
        w = w1[k + 3]; v = xv[k + 3]; ac3 += w.x * v.x + w.y * v.y + w.z * v.z + w.w * v.w;
      }
#pragma unroll 8
      for (int k = 0; k < HID / 4; k += 4) {
        float4 w, v;
        w = w2[k + 0]; v = hv[k + 0]; ac0 += w.x * v.x + w.y * v.y + w.z * v.z + w.w * v.w;
        w = w2[k + 1]; v = hv[k + 1]; ac1 += w.x * v.x + w.y * v.y + w.z * v.z + w.w * v.w;
        w = w2[k + 2]; v = hv[k + 2]; ac2 += w.x * v.x + w.y * v.y + w.z * v.z + w.w * v.w;
        w = w2[k + 3]; v = hv[k + 3]; ac3 += w.x * v.x + w.y * v.y + w.z * v.z + w.w * v.w;
      }
      gbuf[gl][b] = (ac0 + ac1) + (ac2 + ac3);
    }
    __syncthreads();
    if (active && tid < 64) {
      const int b2 = tid & 15, h2l = tid >> 4;
      float iv = sigf(gbuf[h2l][b2]);
      float fv = sigf(gbuf[4 + h2l][b2]);
      float gv = tanhf(gbuf[8 + h2l][b2]);
      float ov = sigf(gbuf[12 + h2l][b2]);
      float cn = fv * c_lds[h2l][b2] + iv * gv;
      c_lds[h2l][b2] = cn;
      float hn = ov * tanhf(cn);
      float* hout = ((l == 0) ? h1 : h2) + (size_t)(t & 1) * NB * HID;
      hout[b2 * HID + slice * 4 + h2l] = hn;
      if (l == 1)
        outs[((size_t)b2 * SEQ + t) * HID + slice * 4 + h2l] = __float2bfloat16(hn);
    }
    gbar(bar, gid);
  }
}

// ---------------- FC GEMM: C[4096,32000] = A[4096,512](bf16) * B^T[32000,512](bf16) + bias ----------------
// m97-style: 128x128 tile, BK=32, global_load_lds width 16, 4 waves (2x2), 4x4 frags/wave.
__global__ __launch_bounds__(256) void fc_gemm(const __hip_bfloat16* __restrict__ A,
                                               const __hip_bfloat16* __restrict__ Bw,
                                               const float* __restrict__ bias,
                                               float* __restrict__ C) {
  __shared__ __align__(16) unsigned short lds_a[128 * 32];
  __shared__ __align__(16) unsigned short lds_b[128 * 32];
  const int tid = threadIdx.x;
  const int lane = tid & 63, wid = tid >> 6;
  const int m0 = blockIdx.y * 128, n0 = blockIdx.x * 128;
  const char* Ab = (const char*)A;   // row stride 1024 B (K=512 bf16)
  const char* Bb = (const char*)Bw;  // row stride 1024 B
  const int ra = tid >> 2;           // 0..63 rows per staging instr
  const int cb = (tid & 3) * 16;     // byte offset within 64B row-chunk
  f32x4 acc[4][4] = {};
  const int wm = (wid >> 1) * 64, wn = (wid & 1) * 64;
  const int fr = lane & 15, fk = (lane >> 4) * 8;
  for (int k0 = 0; k0 < HID; k0 += 32) {
    ld_lds16(Ab + (size_t)(m0 + ra) * 1024 + k0 * 2 + cb, (char*)lds_a + wid * 1024);
    ld_lds16(Ab + (size_t)(m0 + 64 + ra) * 1024 + k0 * 2 + cb,
             (char*)lds_a + 4096 + wid * 1024);
    ld_lds16(Bb + (size_t)(n0 + ra) * 1024 + k0 * 2 + cb, (char*)lds_b + wid * 1024);
    ld_lds16(Bb + (size_t)(n0 + 64 + ra) * 1024 + k0 * 2 + cb,
             (char*)lds_b + 4096 + wid * 1024);
    __syncthreads();
    bf16x8 af[4], bf[4];
#pragma unroll
    for (int i = 0; i < 4; ++i)
      af[i] = *(const bf16x8*)&lds_a[(wm + i * 16 + fr) * 32 + fk];
#pragma unroll
    for (int j = 0; j < 4; ++j)
      bf[j] = *(const bf16x8*)&lds_b[(wn + j * 16 + fr) * 32 + fk];
#pragma unroll
    for (int i = 0; i < 4; ++i)
#pragma unroll
      for (int j = 0; j < 4; ++j)
        acc[i][j] = __builtin_amdgcn_mfma_f32_16x16x32_bf16(af[i], bf[j], acc[i][j], 0, 0, 0);
    __syncthreads();
  }
  const int cr = (lane >> 4) * 4, cc = lane & 15;
  float bv[4];
#pragma unroll
  for (int jj = 0; jj < 4; ++jj) bv[jj] = bias[n0 + wn + jj * 16 + cc];
#pragma unroll
  for (int i = 0; i < 4; ++i) {
#pragma unroll
    for (int jj = 0; jj < 4; ++jj) {
      size_t base = (size_t)(m0 + wm + i * 16 + cr) * VOC + (size_t)(n0 + wn + jj * 16 + cc);
#pragma unroll
      for (int r = 0; r < 4; ++r) C[base + (size_t)r * VOC] = acc[i][jj][r] + bv[jj];
    }
  }
}

extern "C" void kernel_launch(void* const* d_in, const int* in_sizes, int n_in,
                              void* d_out, int out_size, void* d_ws, size_t ws_size,
                              hipStream_t stream) {
  const int* x = (const int*)d_in[0];
  const float* emb = (const float*)d_in[1];
  const float* Wih = (const float*)d_in[2];
  const float* Whh = (const float*)d_in[3];
  const float* bias = (const float*)d_in[4];
  const float* fcw = (const float*)d_in[5];
  const float* fcb = (const float*)d_in[6];
  float* out = (float*)d_out;
  char* ws = (char*)d_ws;

  // ws layout (bytes):
  //   [0, 8192)           tree barrier (root/grp/mirror lines)
  //   [8192, 73728)       h1[2][16][512] f32
  //   [73728, 139264)     h2[2][16][512] f32
  //   [139264, 8527872)   xe[256][16][512] f32
  //   [8527872, 12722176) outs bf16 [16][256][512]
  //   [12722176, 45490176) fcw bf16 [32000][512]
  unsigned* bar = (unsigned*)ws;
  float* h1 = (float*)(ws + 8192);
  float* h2 = (float*)(ws + 73728);
  float* xe = (float*)(ws + 139264);
  __hip_bfloat16* outs_bf = (__hip_bfloat16*)(ws + 8527872);
  uint4* fcw_bf = (uint4*)(ws + 12722176);

  hipMemsetAsync(ws, 0, 139264, stream);  // barrier + h states = 0
  embed_k<<<SEQ * NB, 128, 0, stream>>>(x, emb, xe);
  cvt_k<<<8000, 256, 0, stream>>>(fcw, fcw_bf);  // 8000*256*8 = 16,384,000 elems
  lstm_k<<<256, 256, 0, stream>>>(Wih, Whh, bias, xe, h1, h2, outs_bf, bar);
  fc_gemm<<<dim3(250, 32), 256, 0, stream>>>(outs_bf, (const __hip_bfloat16*)fcw_bf, fcb, out);
}

// Round 3
// 10973.547 us; speedup vs baseline: 1.3703x; 1.2208x over previous
//
#include <hip/hip_runtime.h>
#include <hip/hip_bf16.h>

#define SEQ 256
#define NB 16
#define HID 512
#define VOC 32000

typedef short bf16x8 __attribute__((ext_vector_type(8)));
typedef float f32x4 __attribute__((ext_vector_type(4)));
typedef unsigned short ushort_t;

__device__ __forceinline__ void ld_lds16(const void* g, void* l) {
  __builtin_amdgcn_global_load_lds((const __attribute__((address_space(1))) void*)g,
                                   (__attribute__((address_space(3))) void*)l, 16, 0, 0);
}

__device__ __forceinline__ float sigf(float x) { return 1.0f / (1.0f + expf(-x)); }

__device__ __forceinline__ unsigned pk2(float a, float b) {
  __hip_bfloat16 ha = __float2bfloat16(a), hb = __float2bfloat16(b);
  unsigned short ua = *(unsigned short*)&ha, ub = *(unsigned short*)&hb;
  return (unsigned)ua | ((unsigned)ub << 16);
}

// ---------------- embedding gather -> bf16, chunk-swizzled rows ----------------
// xe[token = t*16+b][512] bf16; 16B-chunk c stored at position c ^ (b&7).
__global__ void embed_k(const int* __restrict__ x, const float* __restrict__ emb,
                        unsigned short* __restrict__ xe) {
  int bid = blockIdx.x;           // token' = t*16 + b
  int t = bid >> 4, b = bid & 15;
  int tok = x[b * SEQ + t];
  const float4* src = (const float4*)(emb + (size_t)tok * HID);
  int e = threadIdx.x;            // chunk 0..63 (8 bf16 each)
  float4 a = src[e * 2], c = src[e * 2 + 1];
  uint4 o;
  o.x = pk2(a.x, a.y); o.y = pk2(a.z, a.w);
  o.z = pk2(c.x, c.y); o.w = pk2(c.z, c.w);
  ((uint4*)(xe + (size_t)bid * HID))[e ^ (b & 7)] = o;
}

// ---------------- f32 -> bf16 pack, 8/thread (for fc weights) ----------------
__global__ void cvt_k(const float* __restrict__ in, uint4* __restrict__ out) {
  size_t i = (size_t)blockIdx.x * blockDim.x + threadIdx.x;
  const float4* in4 = (const float4*)in;
  float4 a = in4[i * 2], b = in4[i * 2 + 1];
  uint4 o;
  o.x = pk2(a.x, a.y); o.y = pk2(a.z, a.w);
  o.z = pk2(b.x, b.y); o.w = pk2(b.z, b.w);
  out[i] = o;
}

// ---------------- two-level tree grid barrier: 32 groups x 16 blocks ----------------
// root @ bar[0]; grp[g] @ bar[32+g*32]; gen-mirror[g] @ bar[1088+g*32].
__device__ __forceinline__ void gbar(unsigned* bar, int gid) {
  __syncthreads();
  if (threadIdx.x == 0) {
    unsigned* grp = bar + 32 + gid * 32;
    unsigned* mir = bar + 1088 + gid * 32;
    unsigned g = __hip_atomic_load(mir, __ATOMIC_ACQUIRE, __HIP_MEMORY_SCOPE_AGENT);
    __threadfence();  // publish this block's global writes
    bool done = false;
    unsigned a = __hip_atomic_fetch_add(grp, 1u, __ATOMIC_ACQ_REL, __HIP_MEMORY_SCOPE_AGENT);
    if (a == 15u) {
      __hip_atomic_store(grp, 0u, __ATOMIC_RELAXED, __HIP_MEMORY_SCOPE_AGENT);
      unsigned r = __hip_atomic_fetch_add(bar, 1u, __ATOMIC_ACQ_REL, __HIP_MEMORY_SCOPE_AGENT);
      if (r == 31u) {
        __hip_atomic_store(bar, 0u, __ATOMIC_RELAXED, __HIP_MEMORY_SCOPE_AGENT);
#pragma unroll
        for (int q = 0; q < 32; ++q)
          __hip_atomic_store(bar + 1088 + q * 32, g + 1u, __ATOMIC_RELEASE,
                             __HIP_MEMORY_SCOPE_AGENT);
        done = true;
      }
    }
    if (!done)
      while (__hip_atomic_load(mir, __ATOMIC_RELAXED, __HIP_MEMORY_SCOPE_AGENT) == g)
        __builtin_amdgcn_s_sleep(2);
    __threadfence();  // invalidate stale cached lines before next phase reads
  }
  __syncthreads();
}

// ---------------- persistent LSTM: 512 blocks, weights LDS-resident, MFMA ----------------
// Layer l = bid>>8 (256 blocks each). Block owns 8 gate rows: 2 h-cols (hc0=(bid&255)*2) x 4 gate types.
// LDS: w_lds 32KB (8 rows x SK bf16, swizzled), b_lds 32KB (2 staged regions [16][512] bf16).
// Layer0: SK=1536 = [Wih | Whh_hi | Whh_lo]; B = [x | h0 | h0].
// Layer1: SK=2048 = [Wih_hi | Wih_lo | Whh_hi | Whh_lo]; B = [h0 | h0 | h1 | h1].
// Phase p: layer0 computes t=p, layer1 t=p-1 (wavefront). 257 phases.
__global__ __launch_bounds__(256) void lstm_k(
    const float* __restrict__ Wih, const float* __restrict__ Whh,
    const float* __restrict__ bias, const unsigned short* __restrict__ xe,
    unsigned short* __restrict__ h0g, unsigned short* __restrict__ h1g,
    unsigned short* __restrict__ outs, unsigned* bar) {
  __shared__ __align__(16) unsigned short w_lds[8 * 2048];  // 32KB
  __shared__ __align__(16) unsigned short b_lds[2 * 8192];  // 32KB
  const int tid = threadIdx.x, bid = blockIdx.x;
  const int lay = bid >> 8, r8 = bid & 255;
  const int hc0 = r8 * 2;
  const int wid = tid >> 6, lane = tid & 63;
  const int gid = bid >> 4;
  const int SK = lay ? 2048 : 1536;
  const int NC = SK >> 3;

  // ---- one-time: weights -> LDS bf16 (hi/lo split), chunk-swizzled (c ^ row) ----
  {
    const int rl = tid >> 5, g = tid & 31;  // 8 rows x 32 threads
    const int q = rl >> 1, hl = rl & 1;
    const int j = q * HID + hc0 + hl;
    const float* wih_row = Wih + ((size_t)lay * 2048 + j) * HID;
    const float* whh_row = Whh + ((size_t)lay * 2048 + j) * HID;
    for (int c = g; c < NC; c += 32) {
      const float* srcrow;
      int off;
      bool lo;
      if (lay == 0) {
        if (c < 64)       { srcrow = wih_row; off = c * 8;         lo = false; }
        else if (c < 128) { srcrow = whh_row; off = (c - 64) * 8;  lo = false; }
        else              { srcrow = whh_row; off = (c - 128) * 8; lo = true;  }
      } else {
        if (c < 64)       { srcrow = wih_row; off = c * 8;         lo = false; }
        else if (c < 128) { srcrow = wih_row; off = (c - 64) * 8;  lo = true;  }
        else if (c < 192) { srcrow = whh_row; off = (c - 128) * 8; lo = false; }
        else              { srcrow = whh_row; off = (c - 192) * 8; lo = true;  }
      }
      unsigned short u[8];
#pragma unroll
      for (int i = 0; i < 8; ++i) {
        float v = srcrow[off + i];
        __hip_bfloat16 h = __float2bfloat16(v);
        if (lo) h = __float2bfloat16(v - __bfloat162float(h));
        u[i] = *(unsigned short*)&h;
      }
      uint4 pk;
      pk.x = (unsigned)u[0] | ((unsigned)u[1] << 16);
      pk.y = (unsigned)u[2] | ((unsigned)u[3] << 16);
      pk.z = (unsigned)u[4] | ((unsigned)u[5] << 16);
      pk.w = (unsigned)u[6] | ((unsigned)u[7] << 16);
      *(uint4*)((char*)w_lds + rl * (SK * 2) + ((c ^ rl) << 4)) = pk;
    }
  }
  const int eb = lane & 15, ehl = lane >> 4;  // epilogue mapping (wave0, lane<32)
  float bq[4] = {0.f, 0.f, 0.f, 0.f};
  float c_reg = 0.f;
  if (wid == 0 && lane < 32) {
#pragma unroll
    for (int q = 0; q < 4; ++q) bq[q] = bias[lay * 2048 + q * HID + hc0 + ehl];
  }
  __syncthreads();

  for (int p = 0; p <= SEQ; ++p) {
    const int t = lay ? p - 1 : p;
    const bool active = lay ? (p >= 1) : (p < SEQ);
    if (active) {
      const char* s0 = lay ? (const char*)(h0g + (size_t)((p - 1) & 1) * 8192)
                           : (const char*)(xe + (size_t)t * 8192);
      const char* s1 = lay ? (const char*)(h1g + (size_t)(p & 1) * 8192)
                           : (const char*)(h0g + (size_t)((p - 1) & 1) * 8192);
#pragma unroll
      for (int r = 0; r < 4; ++r)
        ld_lds16(s0 + r * 4096 + tid * 16, (char*)b_lds + r * 4096 + wid * 1024);
#pragma unroll
      for (int r = 0; r < 4; ++r)
        ld_lds16(s1 + r * 4096 + tid * 16, (char*)b_lds + 16384 + r * 4096 + wid * 1024);
    }
    __syncthreads();  // staging landed (compiler drains vmcnt before barrier)

    f32x4 acc = {0.f, 0.f, 0.f, 0.f};
    if (active) {
      const int fr7 = lane & 7;   // A row (lanes 8-15 duplicate 0-7: broadcast)
      const int hi = lane >> 4;   // k-subchunk
      const int b16 = lane & 15;  // B row (batch)
      const int swb = b16 & 7;
      if (lay) {
#pragma unroll
        for (int s = 0; s < 16; ++s) {
          const int k0 = wid * 512 + s * 32;
          const int ca = (k0 >> 3) + hi;
          bf16x8 a = *(const bf16x8*)((const char*)w_lds + fr7 * 4096 + ((ca ^ fr7) << 4));
          const int reg = k0 >> 10, kl = k0 & 511;
          const int cb = (kl >> 3) + hi;
          bf16x8 bv = *(const bf16x8*)((const char*)b_lds + reg * 16384 + b16 * 1024 +
                                       ((cb ^ swb) << 4));
          acc = __builtin_amdgcn_mfma_f32_16x16x32_bf16(a, bv, acc, 0, 0, 0);
        }
      } else {
#pragma unroll
        for (int s = 0; s < 12; ++s) {
          const int k0 = wid * 384 + s * 32;
          const int ca = (k0 >> 3) + hi;
          bf16x8 a = *(const bf16x8*)((const char*)w_lds + fr7 * 3072 + ((ca ^ fr7) << 4));
          const int reg = (k0 >= 512) ? 1 : 0;
          const int kl = reg ? ((k0 - 512) & 511) : k0;
          const int cb = (kl >> 3) + hi;
          bf16x8 bv = *(const bf16x8*)((const char*)b_lds + reg * 16384 + b16 * 1024 +
                                       ((cb ^ swb) << 4));
          acc = __builtin_amdgcn_mfma_f32_16x16x32_bf16(a, bv, acc, 0, 0, 0);
        }
      }
    }
    __syncthreads();  // all b_lds reads done -> reuse as partial-sum buffer
    float* pbuf = (float*)b_lds;
    if (active && lane < 32) {
      const int rbase = (lane >> 4) * 4;  // D row group: rows 0..7 valid
#pragma unroll
      for (int r = 0; r < 4; ++r)
        pbuf[(wid * 8 + rbase + r) * 16 + (lane & 15)] = acc[r];
    }
    __syncthreads();
    if (active && wid == 0 && lane < 32) {
      float pre[4];
#pragma unroll
      for (int q = 0; q < 4; ++q) {
        const int rl = q * 2 + ehl;
        pre[q] = bq[q] + pbuf[(0 * 8 + rl) * 16 + eb] + pbuf[(1 * 8 + rl) * 16 + eb] +
                 pbuf[(2 * 8 + rl) * 16 + eb] + pbuf[(3 * 8 + rl) * 16 + eb];
      }
      float iv = sigf(pre[0]), fv = sigf(pre[1]);
      float gv = tanhf(pre[2]), ov = sigf(pre[3]);
      c_reg = fv * c_reg + iv * gv;
      float hn = ov * tanhf(c_reg);
      __hip_bfloat16 hh = __float2bfloat16(hn);
      unsigned short hb = *(unsigned short*)&hh;
      const int hc = hc0 + ehl;
      unsigned short* hdst = lay ? h1g : h0g;
      const int par = lay ? ((p - 1) & 1) : (p & 1);
      const int pos = (((hc >> 3) ^ (eb & 7)) << 3) | (hc & 7);  // swizzled within row
      hdst[(size_t)par * 8192 + eb * 512 + pos] = hb;
      if (lay) outs[((size_t)eb * SEQ + t) * HID + hc] = hb;
    }
    gbar(bar, gid);
  }
}

// ---------------- FC GEMM: C[4096,32000] = A[4096,512](bf16) * B^T + bias ----------------
__global__ __launch_bounds__(256) void fc_gemm(const __hip_bfloat16* __restrict__ A,
                                               const __hip_bfloat16* __restrict__ Bw,
                                               const float* __restrict__ bias,
                                               float* __restrict__ C) {
  __shared__ __align__(16) unsigned short lds_a[128 * 32];
  __shared__ __align__(16) unsigned short lds_b[128 * 32];
  const int tid = threadIdx.x;
  const int lane = tid & 63, wid = tid >> 6;
  const int m0 = blockIdx.y * 128, n0 = blockIdx.x * 128;
  const char* Ab = (const char*)A;
  const char* Bb = (const char*)Bw;
  const int ra = tid >> 2;
  const int cb = (tid & 3) * 16;
  f32x4 acc[4][4] = {};
  const int wm = (wid >> 1) * 64, wn = (wid & 1) * 64;
  const int fr = lane & 15, fk = (lane >> 4) * 8;
  for (int k0 = 0; k0 < HID; k0 += 32) {
    ld_lds16(Ab + (size_t)(m0 + ra) * 1024 + k0 * 2 + cb, (char*)lds_a + wid * 1024);
    ld_lds16(Ab + (size_t)(m0 + 64 + ra) * 1024 + k0 * 2 + cb, (char*)lds_a + 4096 + wid * 1024);
    ld_lds16(Bb + (size_t)(n0 + ra) * 1024 + k0 * 2 + cb, (char*)lds_b + wid * 1024);
    ld_lds16(Bb + (size_t)(n0 + 64 + ra) * 1024 + k0 * 2 + cb, (char*)lds_b + 4096 + wid * 1024);
    __syncthreads();
    bf16x8 af[4], bf[4];
#pragma unroll
    for (int i = 0; i < 4; ++i) af[i] = *(const bf16x8*)&lds_a[(wm + i * 16 + fr) * 32 + fk];
#pragma unroll
    for (int j = 0; j < 4; ++j) bf[j] = *(const bf16x8*)&lds_b[(wn + j * 16 + fr) * 32 + fk];
#pragma unroll
    for (int i = 0; i < 4; ++i)
#pragma unroll
      for (int j = 0; j < 4; ++j)
        acc[i][j] = __builtin_amdgcn_mfma_f32_16x16x32_bf16(af[i], bf[j], acc[i][j], 0, 0, 0);
    __syncthreads();
  }
  const int cr = (lane >> 4) * 4, cc = lane & 15;
  float bv[4];
#pragma unroll
  for (int jj = 0; jj < 4; ++jj) bv[jj] = bias[n0 + wn + jj * 16 + cc];
#pragma unroll
  for (int i = 0; i < 4; ++i) {
#pragma unroll
    for (int jj = 0; jj < 4; ++jj) {
      size_t base = (size_t)(m0 + wm + i * 16 + cr) * VOC + (size_t)(n0 + wn + jj * 16 + cc);
#pragma unroll
      for (int r = 0; r < 4; ++r) C[base + (size_t)r * VOC] = acc[i][jj][r] + bv[jj];
    }
  }
}

extern "C" void kernel_launch(void* const* d_in, const int* in_sizes, int n_in,
                              void* d_out, int out_size, void* d_ws, size_t ws_size,
                              hipStream_t stream) {
  const int* x = (const int*)d_in[0];
  const float* emb = (const float*)d_in[1];
  const float* Wih = (const float*)d_in[2];
  const float* Whh = (const float*)d_in[3];
  const float* bias = (const float*)d_in[4];
  const float* fcw = (const float*)d_in[5];
  const float* fcb = (const float*)d_in[6];
  float* out = (float*)d_out;
  char* ws = (char*)d_ws;

  // ws layout (bytes):
  //   [0, 16384)            tree barrier
  //   [16384, 49152)        h0[2][16][512] bf16 (swizzled rows)
  //   [49152, 81920)        h1[2][16][512] bf16
  //   [81920, 4276224)      xe[4096][512] bf16 (swizzled rows)
  //   [4276224, 8470528)    outs[16][256][512] bf16 (linear)
  //   [8470528, 41238528)   fcw bf16 [32000][512]
  unsigned* bar = (unsigned*)ws;
  unsigned short* h0g = (unsigned short*)(ws + 16384);
  unsigned short* h1g = (unsigned short*)(ws + 49152);
  unsigned short* xe = (unsigned short*)(ws + 81920);
  unsigned short* outs = (unsigned short*)(ws + 4276224);
  uint4* fcw_bf = (uint4*)(ws + 8470528);

  hipMemsetAsync(ws, 0, 81920, stream);  // barrier + h states = 0
  embed_k<<<SEQ * NB, 64, 0, stream>>>(x, emb, xe);
  cvt_k<<<8000, 256, 0, stream>>>(fcw, fcw_bf);
  lstm_k<<<512, 256, 0, stream>>>(Wih, Whh, bias, xe, h0g, h1g, outs, bar);
  fc_gemm<<<dim3(250, 32), 256, 0, stream>>>((const __hip_bfloat16*)outs,
                                             (const __hip_bfloat16*)fcw_bf, fcb, out);
}

// Round 4
// 2685.314 us; speedup vs baseline: 5.5998x; 4.0865x over previous
//
#include <hip/hip_runtime.h>
#include <hip/hip_bf16.h>

#define SEQ 256
#define NB 16
#define HID 512
#define VOC 32000
#define HSLOTS 66

typedef short bf16x8 __attribute__((ext_vector_type(8)));
typedef float f32x4 __attribute__((ext_vector_type(4)));
typedef unsigned long long u64;

__device__ __forceinline__ void ld_lds16(const void* g, void* l) {
  __builtin_amdgcn_global_load_lds((const __attribute__((address_space(1))) void*)g,
                                   (__attribute__((address_space(3))) void*)l, 16, 0, 0);
}

__device__ __forceinline__ float sigf(float x) { return 1.0f / (1.0f + expf(-x)); }

__device__ __forceinline__ unsigned pk2(float a, float b) {
  __hip_bfloat16 ha = __float2bfloat16(a), hb = __float2bfloat16(b);
  unsigned short ua = *(unsigned short*)&ha, ub = *(unsigned short*)&hb;
  return (unsigned)ua | ((unsigned)ub << 16);
}

// ---------------- embedding gather -> bf16, plain layout xe[t*16+b][512] ----------------
__global__ void embed_k(const int* __restrict__ x, const float* __restrict__ emb,
                        unsigned short* __restrict__ xe) {
  int bid = blockIdx.x;  // = t*16 + b
  int t = bid >> 4, b = bid & 15;
  int tok = x[b * SEQ + t];
  const float4* src = (const float4*)(emb + (size_t)tok * HID);
  int e = threadIdx.x;  // chunk 0..63 (8 bf16 each)
  float4 a = src[e * 2], c = src[e * 2 + 1];
  uint4 o;
  o.x = pk2(a.x, a.y); o.y = pk2(a.z, a.w);
  o.z = pk2(c.x, c.y); o.w = pk2(c.z, c.w);
  ((uint4*)(xe + (size_t)bid * HID))[e] = o;
}

// ---------------- f32 -> bf16 pack, 8/thread (fc weights) ----------------
__global__ void cvt_k(const float* __restrict__ in, uint4* __restrict__ out) {
  size_t i = (size_t)blockIdx.x * blockDim.x + threadIdx.x;
  const float4* in4 = (const float4*)in;
  float4 a = in4[i * 2], b = in4[i * 2 + 1];
  uint4 o;
  o.x = pk2(a.x, a.y); o.y = pk2(a.z, a.w);
  o.z = pk2(b.x, b.y); o.w = pk2(b.z, b.w);
  out[i] = o;
}

// ---------------- persistent LSTM: 512 blocks, NO barrier, NO fences ----------------
// Block = (lay = bid>>8, r8 = bid&255) owning 8 gate rows (2 h-cols x 4 gates).
// Weights LDS-resident bf16 (hi/lo split on h-facing). B-fragments loaded straight
// from global into MFMA regs via relaxed agent-scope atomics (sc1: fresh cross-XCD).
// Sync: flags[lay][t][g] (64B apart), +1 per block after vmcnt(0); consumers poll ==16.
// h history: 66-slot ring, slot(t) = (t+1)%66, slot0 pre-zeroed = h[-1].
// Ring safety: writer of h0[t] (t>=66) polls flags1[t-66] (readers of h0[t-66] done);
// own-layer flags bound same-layer skew to 1 step.
__global__ __launch_bounds__(256) void lstm_k(
    const float* __restrict__ Wih, const float* __restrict__ Whh,
    const float* __restrict__ bias, const unsigned short* __restrict__ xe,
    unsigned* __restrict__ flags, unsigned short* __restrict__ h0h,
    unsigned short* __restrict__ h1h, unsigned short* __restrict__ outs) {
  __shared__ __align__(16) unsigned short w_lds[8 * 2048];  // 32KB
  __shared__ float pbuf[4][8][16];
  const int tid = threadIdx.x, bid = blockIdx.x;
  const int lay = bid >> 8, r8 = bid & 255, g16 = r8 >> 4;
  const int hc0 = r8 * 2;
  const int wid = tid >> 6, lane = tid & 63;
  const int SK = lay ? 2048 : 1536, NC = SK >> 3;

  // ---- one-time: weights -> LDS bf16 (hi/lo split), chunk-swizzled (c ^ row) ----
  {
    const int rl = tid >> 5, g = tid & 31;  // 8 rows x 32 threads
    const int q = rl >> 1, hl = rl & 1;
    const int j = q * HID + hc0 + hl;
    const float* wih_row = Wih + ((size_t)lay * 2048 + j) * HID;
    const float* whh_row = Whh + ((size_t)lay * 2048 + j) * HID;
    for (int c = g; c < NC; c += 32) {
      const float* srcrow; int off; bool lo;
      if (lay == 0) {
        if (c < 64)       { srcrow = wih_row; off = c * 8;         lo = false; }
        else if (c < 128) { srcrow = whh_row; off = (c - 64) * 8;  lo = false; }
        else              { srcrow = whh_row; off = (c - 128) * 8; lo = true;  }
      } else {
        if (c < 64)       { srcrow = wih_row; off = c * 8;         lo = false; }
        else if (c < 128) { srcrow = wih_row; off = (c - 64) * 8;  lo = true;  }
        else if (c < 192) { srcrow = whh_row; off = (c - 128) * 8; lo = false; }
        else              { srcrow = whh_row; off = (c - 192) * 8; lo = true;  }
      }
      unsigned short u[8];
#pragma unroll
      for (int i = 0; i < 8; ++i) {
        float v = srcrow[off + i];
        __hip_bfloat16 h = __float2bfloat16(v);
        if (lo) h = __float2bfloat16(v - __bfloat162float(h));
        u[i] = *(unsigned short*)&h;
      }
      uint4 pk;
      pk.x = (unsigned)u[0] | ((unsigned)u[1] << 16);
      pk.y = (unsigned)u[2] | ((unsigned)u[3] << 16);
      pk.z = (unsigned)u[4] | ((unsigned)u[5] << 16);
      pk.w = (unsigned)u[6] | ((unsigned)u[7] << 16);
      *(uint4*)((char*)w_lds + rl * (SK * 2) + ((c ^ rl) << 4)) = pk;
    }
  }
  const int eb = lane & 15, ehl = lane >> 4;  // epilogue map (wave0, lanes<32)
  float bq[4] = {0.f, 0.f, 0.f, 0.f};
  float c_reg = 0.f;
  if (wid == 0 && lane < 32) {
#pragma unroll
    for (int q = 0; q < 4; ++q) bq[q] = bias[lay * 2048 + q * HID + hc0 + ehl];
  }
  __syncthreads();

  const int b16 = lane & 15, hi = lane >> 4;  // B col (batch), k-subgroup 0..3
  const int fr7 = lane & 7;                   // A row (8 real rows)
  const int kq = wid * 128;                   // per-wave k-slice within each region
  const int fofs = b16 * HID + kq + hi * 8;   // elem offset within [16][512]
  const int wrow = fr7 * (SK * 2);            // w_lds row byte base

  for (int t = 0; t < SEQ; ++t) {
    // ---- poll dependencies (threads 0..31), then join ----
    if (tid < 32) {
      int pl = -1, pt = 0;
      if (lay == 0) {
        if (tid < 16) { if (t >= 1) { pl = 0; pt = t - 1; } }
        else          { if (t >= HSLOTS) { pl = 1; pt = t - HSLOTS; } }
      } else {
        if (tid < 16) { pl = 0; pt = t; }
        else          { if (t >= 1) { pl = 1; pt = t - 1; } }
      }
      if (pl >= 0) {
        unsigned* fp = flags + (((size_t)pl * SEQ + pt) * 16 + (tid & 15)) * 16;
        while (__hip_atomic_load(fp, __ATOMIC_RELAXED, __HIP_MEMORY_SCOPE_AGENT) < 16u)
          __builtin_amdgcn_s_sleep(1);
      }
    }
    __syncthreads();

    // ---- B fragments: straight to registers (sc1 coherent loads for h) ----
    u64 hfA[4][2], hfB[4][2];
    bf16x8 xf[4];
    if (lay == 0) {
      const unsigned short* hs = h0h + (size_t)(t % HSLOTS) * 8192;  // h0[t-1]
      const unsigned short* xs = xe + (size_t)t * 8192;
#pragma unroll
      for (int s = 0; s < 4; ++s) {
        const unsigned short* p = hs + fofs + s * 32;
        hfA[s][0] = __hip_atomic_load((const u64*)p, __ATOMIC_RELAXED, __HIP_MEMORY_SCOPE_AGENT);
        hfA[s][1] = __hip_atomic_load((const u64*)(p + 4), __ATOMIC_RELAXED, __HIP_MEMORY_SCOPE_AGENT);
        xf[s] = *(const bf16x8*)(xs + fofs + s * 32);  // xe immutable: cacheable
      }
    } else {
      const unsigned short* hs0 = h0h + (size_t)((t + 1) % HSLOTS) * 8192;  // h0[t]
      const unsigned short* hs1 = h1h + (size_t)(t % HSLOTS) * 8192;        // h1[t-1]
#pragma unroll
      for (int s = 0; s < 4; ++s) {
        const unsigned short* p0 = hs0 + fofs + s * 32;
        const unsigned short* p1 = hs1 + fofs + s * 32;
        hfA[s][0] = __hip_atomic_load((const u64*)p0, __ATOMIC_RELAXED, __HIP_MEMORY_SCOPE_AGENT);
        hfA[s][1] = __hip_atomic_load((const u64*)(p0 + 4), __ATOMIC_RELAXED, __HIP_MEMORY_SCOPE_AGENT);
        hfB[s][0] = __hip_atomic_load((const u64*)p1, __ATOMIC_RELAXED, __HIP_MEMORY_SCOPE_AGENT);
        hfB[s][1] = __hip_atomic_load((const u64*)(p1 + 4), __ATOMIC_RELAXED, __HIP_MEMORY_SCOPE_AGENT);
      }
    }

    // ---- MFMA: regions share B (hi/lo reuse) ----
    f32x4 acc = {0.f, 0.f, 0.f, 0.f};
#pragma unroll
    for (int s = 0; s < 4; ++s) {
      const int kk = kq + s * 32 + hi * 8;
      union { u64 q[2]; bf16x8 v; } ua, ub;
      ua.q[0] = hfA[s][0]; ua.q[1] = hfA[s][1];
      if (lay == 0) {
        bf16x8 ax = *(const bf16x8*)((const char*)w_lds + wrow + ((((0    + kk) >> 3) ^ fr7) << 4));
        bf16x8 ah = *(const bf16x8*)((const char*)w_lds + wrow + ((((512  + kk) >> 3) ^ fr7) << 4));
        bf16x8 al = *(const bf16x8*)((const char*)w_lds + wrow + ((((1024 + kk) >> 3) ^ fr7) << 4));
        acc = __builtin_amdgcn_mfma_f32_16x16x32_bf16(ax, xf[s], acc, 0, 0, 0);
        acc = __builtin_amdgcn_mfma_f32_16x16x32_bf16(ah, ua.v, acc, 0, 0, 0);
        acc = __builtin_amdgcn_mfma_f32_16x16x32_bf16(al, ua.v, acc, 0, 0, 0);
      } else {
        ub.q[0] = hfB[s][0]; ub.q[1] = hfB[s][1];
        bf16x8 a0 = *(const bf16x8*)((const char*)w_lds + wrow + ((((0    + kk) >> 3) ^ fr7) << 4));
        bf16x8 a1 = *(const bf16x8*)((const char*)w_lds + wrow + ((((512  + kk) >> 3) ^ fr7) << 4));
        bf16x8 a2 = *(const bf16x8*)((const char*)w_lds + wrow + ((((1024 + kk) >> 3) ^ fr7) << 4));
        bf16x8 a3 = *(const bf16x8*)((const char*)w_lds + wrow + ((((1536 + kk) >> 3) ^ fr7) << 4));
        acc = __builtin_amdgcn_mfma_f32_16x16x32_bf16(a0, ua.v, acc, 0, 0, 0);
        acc = __builtin_amdgcn_mfma_f32_16x16x32_bf16(a1, ua.v, acc, 0, 0, 0);
        acc = __builtin_amdgcn_mfma_f32_16x16x32_bf16(a2, ub.v, acc, 0, 0, 0);
        acc = __builtin_amdgcn_mfma_f32_16x16x32_bf16(a3, ub.v, acc, 0, 0, 0);
      }
    }

    // ---- cross-wave reduce ----
    if (lane < 32) {
      const int rbase = (lane >> 4) * 4;
#pragma unroll
      for (int r = 0; r < 4; ++r) pbuf[wid][rbase + r][lane & 15] = acc[r];
    }
    __syncthreads();

    // ---- epilogue: gates, c/h update, coherent h store, flag ----
    if (wid == 0 && lane < 32) {
      float pre[4];
#pragma unroll
      for (int q = 0; q < 4; ++q) {
        const int rl = q * 2 + ehl;
        pre[q] = bq[q] + pbuf[0][rl][eb] + pbuf[1][rl][eb] + pbuf[2][rl][eb] + pbuf[3][rl][eb];
      }
      float iv = sigf(pre[0]), fv = sigf(pre[1]);
      float gv = tanhf(pre[2]), ov = sigf(pre[3]);
      c_reg = fv * c_reg + iv * gv;
      float hn = ov * tanhf(c_reg);
      __hip_bfloat16 hh = __float2bfloat16(hn);
      unsigned hb = *(unsigned short*)&hh;
      unsigned partner = (unsigned)__shfl_xor((int)hb, 16, 64);
      if (ehl == 0) {
        unsigned dw = hb | (partner << 16);
        unsigned short* hd = (lay ? h1h : h0h) + (size_t)((t + 1) % HSLOTS) * 8192;
        __hip_atomic_store((unsigned*)(hd + eb * HID + hc0), dw, __ATOMIC_RELAXED,
                           __HIP_MEMORY_SCOPE_AGENT);
      }
      if (lay) outs[((size_t)eb * SEQ + t) * HID + hc0 + ehl] = (unsigned short)hb;
    }
    if (wid == 0) {
      asm volatile("s_waitcnt vmcnt(0)" ::: "memory");  // h stores at coherence point
      if (lane == 0)
        __hip_atomic_fetch_add(flags + (((size_t)lay * SEQ + t) * 16 + g16) * 16, 1u,
                               __ATOMIC_RELAXED, __HIP_MEMORY_SCOPE_AGENT);
    }
    __syncthreads();  // pbuf reuse guard
  }
}

// ---------------- FC GEMM: C[4096,32000] = A[4096,512](bf16) * B^T + bias ----------------
__global__ __launch_bounds__(256) void fc_gemm(const __hip_bfloat16* __restrict__ A,
                                               const __hip_bfloat16* __restrict__ Bw,
                                               const float* __restrict__ bias,
                                               float* __restrict__ C) {
  __shared__ __align__(16) unsigned short lds_a[128 * 32];
  __shared__ __align__(16) unsigned short lds_b[128 * 32];
  const int tid = threadIdx.x;
  const int lane = tid & 63, wid = tid >> 6;
  const int m0 = blockIdx.y * 128, n0 = blockIdx.x * 128;
  const char* Ab = (const char*)A;
  const char* Bb = (const char*)Bw;
  const int ra = tid >> 2;
  const int cb = (tid & 3) * 16;
  f32x4 acc[4][4] = {};
  const int wm = (wid >> 1) * 64, wn = (wid & 1) * 64;
  const int fr = lane & 15, fk = (lane >> 4) * 8;
  for (int k0 = 0; k0 < HID; k0 += 32) {
    ld_lds16(Ab + (size_t)(m0 + ra) * 1024 + k0 * 2 + cb, (char*)lds_a + wid * 1024);
    ld_lds16(Ab + (size_t)(m0 + 64 + ra) * 1024 + k0 * 2 + cb, (char*)lds_a + 4096 + wid * 1024);
    ld_lds16(Bb + (size_t)(n0 + ra) * 1024 + k0 * 2 + cb, (char*)lds_b + wid * 1024);
    ld_lds16(Bb + (size_t)(n0 + 64 + ra) * 1024 + k0 * 2 + cb, (char*)lds_b + 4096 + wid * 1024);
    __syncthreads();
    bf16x8 af[4], bf[4];
#pragma unroll
    for (int i = 0; i < 4; ++i) af[i] = *(const bf16x8*)&lds_a[(wm + i * 16 + fr) * 32 + fk];
#pragma unroll
    for (int j = 0; j < 4; ++j) bf[j] = *(const bf16x8*)&lds_b[(wn + j * 16 + fr) * 32 + fk];
#pragma unroll
    for (int i = 0; i < 4; ++i)
#pragma unroll
      for (int j = 0; j < 4; ++j)
        acc[i][j] = __builtin_amdgcn_mfma_f32_16x16x32_bf16(af[i], bf[j], acc[i][j], 0, 0, 0);
    __syncthreads();
  }
  const int cr = (lane >> 4) * 4, cc = lane & 15;
  float bv[4];
#pragma unroll
  for (int jj = 0; jj < 4; ++jj) bv[jj] = bias[n0 + wn + jj * 16 + cc];
#pragma unroll
  for (int i = 0; i < 4; ++i) {
#pragma unroll
    for (int jj = 0; jj < 4; ++jj) {
      size_t base = (size_t)(m0 + wm + i * 16 + cr) * VOC + (size_t)(n0 + wn + jj * 16 + cc);
#pragma unroll
      for (int r = 0; r < 4; ++r) C[base + (size_t)r * VOC] = acc[i][jj][r] + bv[jj];
    }
  }
}

extern "C" void kernel_launch(void* const* d_in, const int* in_sizes, int n_in,
                              void* d_out, int out_size, void* d_ws, size_t ws_size,
                              hipStream_t stream) {
  const int* x = (const int*)d_in[0];
  const float* emb = (const float*)d_in[1];
  const float* Wih = (const float*)d_in[2];
  const float* Whh = (const float*)d_in[3];
  const float* bias = (const float*)d_in[4];
  const float* fcw = (const float*)d_in[5];
  const float* fcb = (const float*)d_in[6];
  float* out = (float*)d_out;
  char* ws = (char*)d_ws;

  // ws layout (bytes):
  //   [0, 524288)           flags[2][256][16] @ 64B stride
  //   [524288, 1605632)     h0 ring: 66 slots x 16KB (slot0 = zeros)
  //   [1605632, 2686976)    h1 ring: 66 slots x 16KB
  //   [2686976, 6881280)    xe[4096][512] bf16
  //   [6881280, 11075584)   outs[16][256][512] bf16
  //   [11075584, 43843584)  fcw bf16 [32000][512]   (total 43.8 MB)
  unsigned* flags = (unsigned*)ws;
  unsigned short* h0h = (unsigned short*)(ws + 524288);
  unsigned short* h1h = (unsigned short*)(ws + 1605632);
  unsigned short* xe = (unsigned short*)(ws + 2686976);
  unsigned short* outs = (unsigned short*)(ws + 6881280);
  uint4* fcw_bf = (uint4*)(ws + 11075584);

  hipMemsetAsync(ws, 0, 540672, stream);            // flags + h0 slot0
  hipMemsetAsync(ws + 1605632, 0, 16384, stream);   // h1 slot0
  embed_k<<<SEQ * NB, 64, 0, stream>>>(x, emb, xe);
  cvt_k<<<8000, 256, 0, stream>>>(fcw, fcw_bf);
  lstm_k<<<512, 256, 0, stream>>>(Wih, Whh, bias, xe, flags, h0h, h1h, outs);
  fc_gemm<<<dim3(250, 32), 256, 0, stream>>>((const __hip_bfloat16*)outs,
                                             (const __hip_bfloat16*)fcw_bf, fcb, out);
}

// Round 5
// 1738.938 us; speedup vs baseline: 8.6474x; 1.5442x over previous
//
#include <hip/hip_runtime.h>
#include <hip/hip_bf16.h>

#define SEQ 256
#define NB 16
#define HID 512
#define VOC 32000

typedef short bf16x8 __attribute__((ext_vector_type(8)));
typedef float f32x4 __attribute__((ext_vector_type(4)));
typedef unsigned long long u64;

__device__ __forceinline__ void ld_lds16(const void* g, void* l) {
  __builtin_amdgcn_global_load_lds((const __attribute__((address_space(1))) void*)g,
                                   (__attribute__((address_space(3))) void*)l, 16, 0, 0);
}

__device__ __forceinline__ float sigf(float x) { return 1.0f / (1.0f + expf(-x)); }

__device__ __forceinline__ unsigned pk2(float a, float b) {
  __hip_bfloat16 ha = __float2bfloat16(a), hb = __float2bfloat16(b);
  unsigned short ua = *(unsigned short*)&ha, ub = *(unsigned short*)&hb;
  return (unsigned)ua | ((unsigned)ub << 16);
}

// ---------------- embedding gather -> bf16, xe[t*16+b][512] ----------------
__global__ void embed_k(const int* __restrict__ x, const float* __restrict__ emb,
                        unsigned short* __restrict__ xe) {
  int bid = blockIdx.x;  // = t*16 + b
  int t = bid >> 4, b = bid & 15;
  int tok = x[b * SEQ + t];
  const float4* src = (const float4*)(emb + (size_t)tok * HID);
  int e = threadIdx.x;
  float4 a = src[e * 2], c = src[e * 2 + 1];
  uint4 o;
  o.x = pk2(a.x, a.y); o.y = pk2(a.z, a.w);
  o.z = pk2(c.x, c.y); o.w = pk2(c.z, c.w);
  ((uint4*)(xe + (size_t)bid * HID))[e] = o;
}

// ---------------- f32 -> bf16 pack, 8/thread ----------------
__global__ void cvt_k(const float* __restrict__ in, uint4* __restrict__ out) {
  size_t i = (size_t)blockIdx.x * blockDim.x + threadIdx.x;
  const float4* in4 = (const float4*)in;
  float4 a = in4[i * 2], b = in4[i * 2 + 1];
  uint4 o;
  o.x = pk2(a.x, a.y); o.y = pk2(a.z, a.w);
  o.z = pk2(b.x, b.y); o.w = pk2(b.z, b.w);
  out[i] = o;
}

// ---------------- gx GEMM: gx[4096][2048] f32 = xe[4096][512] @ Wih0^T (no bias) ----------------
__global__ __launch_bounds__(256) void gx_gemm(const __hip_bfloat16* __restrict__ A,
                                               const __hip_bfloat16* __restrict__ Bw,
                                               float* __restrict__ C) {
  __shared__ __align__(16) unsigned short lds_a[128 * 32];
  __shared__ __align__(16) unsigned short lds_b[128 * 32];
  const int tid = threadIdx.x;
  const int lane = tid & 63, wid = tid >> 6;
  const int m0 = blockIdx.y * 128, n0 = blockIdx.x * 128;
  const char* Ab = (const char*)A;
  const char* Bb = (const char*)Bw;
  const int ra = tid >> 2, cb = (tid & 3) * 16;
  f32x4 acc[4][4] = {};
  const int wm = (wid >> 1) * 64, wn = (wid & 1) * 64;
  const int fr = lane & 15, fk = (lane >> 4) * 8;
  for (int k0 = 0; k0 < HID; k0 += 32) {
    ld_lds16(Ab + (size_t)(m0 + ra) * 1024 + k0 * 2 + cb, (char*)lds_a + wid * 1024);
    ld_lds16(Ab + (size_t)(m0 + 64 + ra) * 1024 + k0 * 2 + cb, (char*)lds_a + 4096 + wid * 1024);
    ld_lds16(Bb + (size_t)(n0 + ra) * 1024 + k0 * 2 + cb, (char*)lds_b + wid * 1024);
    ld_lds16(Bb + (size_t)(n0 + 64 + ra) * 1024 + k0 * 2 + cb, (char*)lds_b + 4096 + wid * 1024);
    __syncthreads();
    bf16x8 af[4], bf[4];
#pragma unroll
    for (int i = 0; i < 4; ++i) af[i] = *(const bf16x8*)&lds_a[(wm + i * 16 + fr) * 32 + fk];
#pragma unroll
    for (int j = 0; j < 4; ++j) bf[j] = *(const bf16x8*)&lds_b[(wn + j * 16 + fr) * 32 + fk];
#pragma unroll
    for (int i = 0; i < 4; ++i)
#pragma unroll
      for (int j = 0; j < 4; ++j)
        acc[i][j] = __builtin_amdgcn_mfma_f32_16x16x32_bf16(af[i], bf[j], acc[i][j], 0, 0, 0);
    __syncthreads();
  }
  const int cr = (lane >> 4) * 4, cc = lane & 15;
#pragma unroll
  for (int i = 0; i < 4; ++i)
#pragma unroll
    for (int jj = 0; jj < 4; ++jj) {
      size_t base = (size_t)(m0 + wm + i * 16 + cr) * 2048 + (n0 + wn + jj * 16 + cc);
#pragma unroll
      for (int r = 0; r < 4; ++r) C[base + (size_t)r * 2048] = acc[i][jj][r];
    }
}

// ---------------- persistent LSTM: 256 blocks (128/layer), 16 gate rows each ----------------
// lay = bid>>7, r = bid&127, rows j = q*512 + r*4 + hl (q=gate, hl=0..3).
// lay0: K=1024 [Whh_hi|Whh_lo], gx precomputed. lay1: K=2048 [Wih_hi|Wih_lo|Whh_hi|Whh_lo].
// h rings full-size (257 slots): no ring guards; slot t+1 holds h[t]; slot0 = 0.
// flags[lay][t][g8] (g8 = r>>4, 8 words @64B): +1 per block after vmcnt(0); poll >=16.
__global__ __launch_bounds__(256) void lstm_k(
    const float* __restrict__ Wih, const float* __restrict__ Whh,
    const float* __restrict__ bias, const float* __restrict__ gx,
    unsigned* __restrict__ flags, unsigned short* __restrict__ h0h,
    unsigned short* __restrict__ h1h) {
  __shared__ __align__(16) unsigned short w_lds[16 * 2048];  // 64KB
  __shared__ float pbuf[4][16][17];
  const int tid = threadIdx.x, bid = blockIdx.x;
  const int lay = bid >> 7, r = bid & 127, g8 = r >> 4;
  const int hc0 = r * 4;
  const int wid = tid >> 6, lane = tid & 63;
  const int SK = lay ? 2048 : 1024, NC = SK >> 3, SKB = SK * 2;

  // ---- one-time: weights -> LDS bf16 hi/lo, chunk-swizzled (c ^ (row&7)) ----
  {
    const int rl = tid >> 4, g = tid & 15;  // 16 rows x 16 threads
    const int q = rl >> 2, hl = rl & 3;
    const int j = q * HID + hc0 + hl;
    const float* wih_row = Wih + ((size_t)lay * 2048 + j) * HID;
    const float* whh_row = Whh + ((size_t)lay * 2048 + j) * HID;
    for (int c = g; c < NC; c += 16) {
      const float* srcrow; int off; bool lo;
      if (lay == 0) {
        if (c < 64) { srcrow = whh_row; off = c * 8;        lo = false; }
        else        { srcrow = whh_row; off = (c - 64) * 8; lo = true;  }
      } else {
        if (c < 64)       { srcrow = wih_row; off = c * 8;         lo = false; }
        else if (c < 128) { srcrow = wih_row; off = (c - 64) * 8;  lo = true;  }
        else if (c < 192) { srcrow = whh_row; off = (c - 128) * 8; lo = false; }
        else              { srcrow = whh_row; off = (c - 192) * 8; lo = true;  }
      }
      unsigned short u[8];
#pragma unroll
      for (int i = 0; i < 8; ++i) {
        float v = srcrow[off + i];
        __hip_bfloat16 h = __float2bfloat16(v);
        if (lo) h = __float2bfloat16(v - __bfloat162float(h));
        u[i] = *(unsigned short*)&h;
      }
      uint4 pk;
      pk.x = (unsigned)u[0] | ((unsigned)u[1] << 16);
      pk.y = (unsigned)u[2] | ((unsigned)u[3] << 16);
      pk.z = (unsigned)u[4] | ((unsigned)u[5] << 16);
      pk.w = (unsigned)u[6] | ((unsigned)u[7] << 16);
      *(uint4*)((char*)w_lds + rl * SKB + ((c ^ (rl & 7)) << 4)) = pk;
    }
  }
  // epilogue mapping: wave0 lane -> (batch b, local h col hl)
  const int eb = lane & 15, ehl = lane >> 4;
  float bq[4], c_reg = 0.f;
  if (wid == 0) {
#pragma unroll
    for (int q = 0; q < 4; ++q) bq[q] = bias[lay * 2048 + q * HID + hc0 + ehl];
  }
  __syncthreads();

  const int b16 = lane & 15, hi = lane >> 4;
  const int fr = lane & 15;                  // A row (16 real rows)
  const int kq = wid * 128;                  // per-wave k-slice of the 512-dim h
  const int fofs = b16 * HID + kq + hi * 8;  // elem offset within [16][512]
  const int wrow = fr * SKB;

  for (int t = 0; t < SEQ; ++t) {
    // ---- early gx loads (lay0, wave0): independent of h ----
    float gxr[4] = {0.f, 0.f, 0.f, 0.f};
    if (lay == 0 && wid == 0) {
      const float* gp = gx + ((size_t)t * 16 + eb) * 2048 + hc0 + ehl;
#pragma unroll
      for (int q = 0; q < 4; ++q) gxr[q] = gp[q * HID];
    }
    // ---- poll deps ----
    if (lay == 0) {
      if (t >= 1 && tid < 8) {
        unsigned* fp = flags + (((size_t)0 * SEQ + (t - 1)) * 8 + tid) * 16;
        while (__hip_atomic_load(fp, __ATOMIC_RELAXED, __HIP_MEMORY_SCOPE_AGENT) < 16u)
          __builtin_amdgcn_s_sleep(1);
      }
    } else {
      if (tid < 8) {
        unsigned* fp = flags + (((size_t)0 * SEQ + t) * 8 + tid) * 16;
        while (__hip_atomic_load(fp, __ATOMIC_RELAXED, __HIP_MEMORY_SCOPE_AGENT) < 16u)
          __builtin_amdgcn_s_sleep(1);
      } else if (tid < 16 && t >= 1) {
        unsigned* fp = flags + (((size_t)1 * SEQ + (t - 1)) * 8 + (tid - 8)) * 16;
        while (__hip_atomic_load(fp, __ATOMIC_RELAXED, __HIP_MEMORY_SCOPE_AGENT) < 16u)
          __builtin_amdgcn_s_sleep(1);
      }
    }
    __syncthreads();

    // ---- B fragments straight to regs (sc1 coherent) ----
    u64 hfA[4][2], hfB[4][2];
    {
      const unsigned short* hsA = lay ? (h0h + (size_t)(t + 1) * 8192)   // h0[t]
                                      : (h0h + (size_t)t * 8192);        // h0[t-1]
#pragma unroll
      for (int s = 0; s < 4; ++s) {
        const unsigned short* p = hsA + fofs + s * 32;
        hfA[s][0] = __hip_atomic_load((const u64*)p, __ATOMIC_RELAXED, __HIP_MEMORY_SCOPE_AGENT);
        hfA[s][1] = __hip_atomic_load((const u64*)(p + 4), __ATOMIC_RELAXED, __HIP_MEMORY_SCOPE_AGENT);
      }
      if (lay) {
        const unsigned short* hsB = h1h + (size_t)t * 8192;              // h1[t-1]
#pragma unroll
        for (int s = 0; s < 4; ++s) {
          const unsigned short* p = hsB + fofs + s * 32;
          hfB[s][0] = __hip_atomic_load((const u64*)p, __ATOMIC_RELAXED, __HIP_MEMORY_SCOPE_AGENT);
          hfB[s][1] = __hip_atomic_load((const u64*)(p + 4), __ATOMIC_RELAXED, __HIP_MEMORY_SCOPE_AGENT);
        }
      }
    }

    // ---- MFMA ----
    f32x4 acc = {0.f, 0.f, 0.f, 0.f};
#pragma unroll
    for (int s = 0; s < 4; ++s) {
      const int kh = kq + s * 32 + hi * 8;  // 0..511 within h
      union { u64 q[2]; bf16x8 v; } ua, ub;
      ua.q[0] = hfA[s][0]; ua.q[1] = hfA[s][1];
      if (lay == 0) {
        bf16x8 ahi = *(const bf16x8*)((const char*)w_lds + wrow + ((((0   + kh) >> 3) ^ (fr & 7)) << 4));
        bf16x8 alo = *(const bf16x8*)((const char*)w_lds + wrow + ((((512 + kh) >> 3) ^ (fr & 7)) << 4));
        acc = __builtin_amdgcn_mfma_f32_16x16x32_bf16(ahi, ua.v, acc, 0, 0, 0);
        acc = __builtin_amdgcn_mfma_f32_16x16x32_bf16(alo, ua.v, acc, 0, 0, 0);
      } else {
        ub.q[0] = hfB[s][0]; ub.q[1] = hfB[s][1];
        bf16x8 a0 = *(const bf16x8*)((const char*)w_lds + wrow + ((((0    + kh) >> 3) ^ (fr & 7)) << 4));
        bf16x8 a1 = *(const bf16x8*)((const char*)w_lds + wrow + ((((512  + kh) >> 3) ^ (fr & 7)) << 4));
        bf16x8 a2 = *(const bf16x8*)((const char*)w_lds + wrow + ((((1024 + kh) >> 3) ^ (fr & 7)) << 4));
        bf16x8 a3 = *(const bf16x8*)((const char*)w_lds + wrow + ((((1536 + kh) >> 3) ^ (fr & 7)) << 4));
        acc = __builtin_amdgcn_mfma_f32_16x16x32_bf16(a0, ua.v, acc, 0, 0, 0);
        acc = __builtin_amdgcn_mfma_f32_16x16x32_bf16(a1, ua.v, acc, 0, 0, 0);
        acc = __builtin_amdgcn_mfma_f32_16x16x32_bf16(a2, ub.v, acc, 0, 0, 0);
        acc = __builtin_amdgcn_mfma_f32_16x16x32_bf16(a3, ub.v, acc, 0, 0, 0);
      }
    }
    // D layout: col = lane&15 (batch), row = (lane>>4)*4 + reg (gate row 0..15)
#pragma unroll
    for (int rr = 0; rr < 4; ++rr) pbuf[wid][(lane >> 4) * 4 + rr][lane & 15] = acc[rr];
    __syncthreads();

    // ---- epilogue: wave0 (64 lanes = 16 b x 4 hl) ----
    if (wid == 0) {
      float pre[4];
#pragma unroll
      for (int q = 0; q < 4; ++q) {
        const int rl = q * 4 + ehl;
        pre[q] = bq[q] + gxr[q] + pbuf[0][rl][eb] + pbuf[1][rl][eb] +
                 pbuf[2][rl][eb] + pbuf[3][rl][eb];
      }
      float iv = sigf(pre[0]), fv = sigf(pre[1]);
      float gv = tanhf(pre[2]), ov = sigf(pre[3]);
      c_reg = fv * c_reg + iv * gv;
      float hn = ov * tanhf(c_reg);
      __hip_bfloat16 hh = __float2bfloat16(hn);
      int hb = (int)*(unsigned short*)&hh;
      int t1 = __shfl(hb, (lane & 15) + 16);
      int t2 = __shfl(hb, (lane & 15) + 32);
      int t3 = __shfl(hb, (lane & 15) + 48);
      if (ehl == 0) {
        u64 dw = (u64)(unsigned short)hb | ((u64)(unsigned short)t1 << 16) |
                 ((u64)(unsigned short)t2 << 32) | ((u64)(unsigned short)t3 << 48);
        unsigned short* hd = (lay ? h1h : h0h) + (size_t)(t + 1) * 8192;
        __hip_atomic_store((u64*)(hd + eb * HID + hc0), dw, __ATOMIC_RELAXED,
                           __HIP_MEMORY_SCOPE_AGENT);
      }
      asm volatile("s_waitcnt vmcnt(0)" ::: "memory");
      if (lane == 0)
        __hip_atomic_fetch_add(flags + (((size_t)lay * SEQ + t) * 8 + g8) * 16, 1u,
                               __ATOMIC_RELAXED, __HIP_MEMORY_SCOPE_AGENT);
    }
    __syncthreads();  // pbuf reuse guard
  }
}

// ---------------- FC GEMM: out[b][t][32000] = h1[t][b][:] @ fcw^T + fcb ----------------
__global__ __launch_bounds__(256) void fc_gemm(const __hip_bfloat16* __restrict__ A,
                                               const __hip_bfloat16* __restrict__ Bw,
                                               const float* __restrict__ bias,
                                               float* __restrict__ C) {
  __shared__ __align__(16) unsigned short lds_a[128 * 32];
  __shared__ __align__(16) unsigned short lds_b[128 * 32];
  const int tid = threadIdx.x;
  const int lane = tid & 63, wid = tid >> 6;
  const int m0 = blockIdx.y * 128, n0 = blockIdx.x * 128;
  const char* Ab = (const char*)A;
  const char* Bb = (const char*)Bw;
  const int ra = tid >> 2, cb = (tid & 3) * 16;
  f32x4 acc[4][4] = {};
  const int wm = (wid >> 1) * 64, wn = (wid & 1) * 64;
  const int fr = lane & 15, fk = (lane >> 4) * 8;
  for (int k0 = 0; k0 < HID; k0 += 32) {
    ld_lds16(Ab + (size_t)(m0 + ra) * 1024 + k0 * 2 + cb, (char*)lds_a + wid * 1024);
    ld_lds16(Ab + (size_t)(m0 + 64 + ra) * 1024 + k0 * 2 + cb, (char*)lds_a + 4096 + wid * 1024);
    ld_lds16(Bb + (size_t)(n0 + ra) * 1024 + k0 * 2 + cb, (char*)lds_b + wid * 1024);
    ld_lds16(Bb + (size_t)(n0 + 64 + ra) * 1024 + k0 * 2 + cb, (char*)lds_b + 4096 + wid * 1024);
    __syncthreads();
    bf16x8 af[4], bf[4];
#pragma unroll
    for (int i = 0; i < 4; ++i) af[i] = *(const bf16x8*)&lds_a[(wm + i * 16 + fr) * 32 + fk];
#pragma unroll
    for (int j = 0; j < 4; ++j) bf[j] = *(const bf16x8*)&lds_b[(wn + j * 16 + fr) * 32 + fk];
#pragma unroll
    for (int i = 0; i < 4; ++i)
#pragma unroll
      for (int j = 0; j < 4; ++j)
        acc[i][j] = __builtin_amdgcn_mfma_f32_16x16x32_bf16(af[i], bf[j], acc[i][j], 0, 0, 0);
    __syncthreads();
  }
  const int cr = (lane >> 4) * 4, cc = lane & 15;
  float bv[4];
#pragma unroll
  for (int jj = 0; jj < 4; ++jj) bv[jj] = bias[n0 + wn + jj * 16 + cc];
#pragma unroll
  for (int i = 0; i < 4; ++i) {
#pragma unroll
    for (int jj = 0; jj < 4; ++jj) {
#pragma unroll
      for (int rr = 0; rr < 4; ++rr) {
        int tok = m0 + wm + i * 16 + cr + rr;               // = t*16 + b
        int orow = (tok & 15) * SEQ + (tok >> 4);           // = b*256 + t
        C[(size_t)orow * VOC + (n0 + wn + jj * 16 + cc)] = acc[i][jj][rr] + bv[jj];
      }
    }
  }
}

extern "C" void kernel_launch(void* const* d_in, const int* in_sizes, int n_in,
                              void* d_out, int out_size, void* d_ws, size_t ws_size,
                              hipStream_t stream) {
  const int* x = (const int*)d_in[0];
  const float* emb = (const float*)d_in[1];
  const float* Wih = (const float*)d_in[2];
  const float* Whh = (const float*)d_in[3];
  const float* bias = (const float*)d_in[4];
  const float* fcw = (const float*)d_in[5];
  const float* fcb = (const float*)d_in[6];
  float* out = (float*)d_out;
  char* ws = (char*)d_ws;

  // ws layout (bytes):
  //   [0, 262144)           flags[2][256][8] @ 64B stride
  //   [262144, 4472832)     h0 ring: 257 slots x 16KB (slot0 = 0)
  //   [4472832, 8683520)    h1 ring: 257 slots x 16KB (slot0 = 0; slots 1.. = outs)
  //   [8683520, 12877824)   xe[4096][512] bf16
  //   [12877824, 46432256)  gx[4096][2048] f32
  //   [46432256, 48529408)  wih0 bf16 [2048][512]
  //   fcw_bf aliases [8683520, 41451520) over xe+gx (written after lstm_k)
  unsigned* flags = (unsigned*)ws;
  unsigned short* h0h = (unsigned short*)(ws + 262144);
  unsigned short* h1h = (unsigned short*)(ws + 4472832);
  unsigned short* xe = (unsigned short*)(ws + 8683520);
  float* gx = (float*)(ws + 12877824);
  uint4* wih0_bf = (uint4*)(ws + 46432256);
  uint4* fcw_bf = (uint4*)(ws + 8683520);

  hipMemsetAsync(ws, 0, 262144 + 16384, stream);   // flags + h0 slot0
  hipMemsetAsync(ws + 4472832, 0, 16384, stream);  // h1 slot0
  embed_k<<<SEQ * NB, 64, 0, stream>>>(x, emb, xe);
  cvt_k<<<512, 256, 0, stream>>>(Wih, wih0_bf);    // layer-0 Wih only (1M elems)
  gx_gemm<<<dim3(16, 32), 256, 0, stream>>>((const __hip_bfloat16*)xe,
                                            (const __hip_bfloat16*)wih0_bf, gx);
  lstm_k<<<256, 256, 0, stream>>>(Wih, Whh, bias, gx, flags, h0h, h1h);
  cvt_k<<<8000, 256, 0, stream>>>(fcw, fcw_bf);    // after lstm: aliases xe/gx
  fc_gemm<<<dim3(250, 32), 256, 0, stream>>>((const __hip_bfloat16*)(h1h + 8192),
                                             (const __hip_bfloat16*)fcw_bf, fcb, out);
}